// Round 2
// baseline (759.819 us; speedup 1.0000x reference)
//
#include <hip/hip_runtime.h>

#define NB 8
#define SSIZE (1u << 24)

// Flat index convention (jnp reshape of (2,)*24): wire w <-> bit b = 23-w.
// Stage S_t = RY(bit t) + CNOT(ctrl bit t+1, tgt bit t), applied t = 23..0.
// Dependencies: (k,t) <- (k,t+1) and (k-1, {t-1,t,t+1}) (light cone).
//
// Light-cone fused schedule (validated round 1), windows:
//   H = bits {0,1} u {12..23}  (block idx m = bits 2..11)
//   L = bits {0..13}           (block idx m = bits 14..23, contiguous 64KB)
// Per H+L pair, THREE circuit blocks retire => 6 sweeps total.
//
// NUMERICS: state evolves in fp64 registers inside each kernel; global state
// between sweeps is fp32 (6 boundary roundings instead of a 168-stage fp32
// random walk). LDS transposes are EXACT: each double moves as lo-word pass +
// hi-word pass through the 64KB tile. Coefs/mean in fp64.
//
// dws layout (doubles): [0]=sum, [8 + k*24 + w]=cos(theta/2), [200+...]=sin.

__global__ void k_prep(const float* __restrict__ ang, double* __restrict__ dws) {
    int t = threadIdx.x;
    if (t == 0) dws[0] = 0.0;
    if (t < NB * 24) {
        double a = 0.5 * (double)ang[t];
        dws[8 + t]   = cos(a);
        dws[200 + t] = sin(a);
    }
}

// ---- helpers ----------------------------------------------------------

__device__ __forceinline__ unsigned sw(unsigned f) {
    return f ^ (((f >> 3) ^ (f >> 5)) & 7u);
}

__device__ __forceinline__ void ry2d(double& a0, double& a1, double c, double s, bool ctl) {
    double w0 = c * a0 - s * a1;
    double w1 = s * a0 + c * a1;
    a0 = ctl ? w1 : w0;
    a1 = ctl ? w0 : w1;
}

// Stage on 8xdouble4 granule: elem bits {0,1}=d, {2,3,4}=register index jj.
template<int TB, int MODE>
__device__ __forceinline__ void stage8d(double4* x, double c, double s) {
#pragma unroll
    for (int j0 = 0; j0 < 8; ++j0) {
        if (j0 & (1 << TB)) continue;
        const int j1 = j0 | (1 << TB);
        const bool ctl = (MODE == 1) || (MODE == 0 && ((j0 >> (TB + 1)) & 1));
        ry2d(x[j0].x, x[j1].x, c, s, ctl);
        ry2d(x[j0].y, x[j1].y, c, s, ctl);
        ry2d(x[j0].z, x[j1].z, c, s, ctl);
        ry2d(x[j0].w, x[j1].w, c, s, ctl);
    }
}

__device__ __forceinline__ void coefs_d(unsigned lane, int lb, bool g,
                                        double c, double s, double& cA, double& cP) {
    bool b = (lane >> lb) & 1u;
    cA = g ? (b ? -s : s) : c;
    cP = g ? c : (b ? s : -s);
}

__device__ __forceinline__ void lane_stage_d(double4* x, int mask, double cA, double cP) {
#pragma unroll
    for (int j = 0; j < 8; ++j) {
        double px = __shfl_xor(x[j].x, mask, 64);
        double py = __shfl_xor(x[j].y, mask, 64);
        double pz = __shfl_xor(x[j].z, mask, 64);
        double pw = __shfl_xor(x[j].w, mask, 64);
        x[j].x = cA * x[j].x + cP * px;
        x[j].y = cA * x[j].y + cP * py;
        x[j].z = cA * x[j].z + cP * pz;
        x[j].w = cA * x[j].w + cP * pw;
    }
}

__device__ __forceinline__ void lane_stage_jc_d(double4* x, int mask,
                                                double cA0, double cP0,
                                                double cA1, double cP1) {
#pragma unroll
    for (int j = 0; j < 8; ++j) {
        double cA = (j & 1) ? cA1 : cA0;
        double cP = (j & 1) ? cP1 : cP0;
        double px = __shfl_xor(x[j].x, mask, 64);
        double py = __shfl_xor(x[j].y, mask, 64);
        double pz = __shfl_xor(x[j].z, mask, 64);
        double pw = __shfl_xor(x[j].w, mask, 64);
        x[j].x = cA * x[j].x + cP * px;
        x[j].y = cA * x[j].y + cP * py;
        x[j].z = cA * x[j].z + cP * pz;
        x[j].w = cA * x[j].w + cP * pw;
    }
}

// S1 (tgt d1, ctrl = runtime bool g1) then S0 (tgt d0, ctrl d1).
__device__ __forceinline__ void dstages_d(double4* x, double c1, double s1, bool g1,
                                          double c0, double s0) {
#pragma unroll
    for (int j = 0; j < 8; ++j) {
        ry2d(x[j].x, x[j].z, c1, s1, g1);
        ry2d(x[j].y, x[j].w, c1, s1, g1);
        ry2d(x[j].x, x[j].y, c0, s0, false);
        ry2d(x[j].z, x[j].w, c0, s0, true);
    }
}

// x = (0.6*tanh(0.1*2^23*v^2))^0.15; small-z series avoids cancellation.
__device__ __forceinline__ float xform(float z) {
    float e2 = __builtin_amdgcn_exp2f(z * 2.8853900817779268f);   // e^(2z)
    float big = 1.0f - 2.0f * __builtin_amdgcn_rcpf(e2 + 1.0f);
    float z2 = z * z;
    float small_ = z * (1.0f - 0.33333333f * z2 * (1.0f - 0.4f * z2));
    float t = (z < 0.04f) ? small_ : big;
    return __builtin_amdgcn_exp2f(0.15f * __builtin_amdgcn_logf(0.6f * t));
}

// ---- exact fp64 LDS transposes (lo/hi word two-pass through 64KB tile) ---
// layout1: w = tid | (jj<<9)   layout2: w = lane | (jj<<6) | ((tid>>6)<<9)

__device__ __forceinline__ float4 lo4(const double4 v) {
    return make_float4(__int_as_float(__double2loint(v.x)),
                       __int_as_float(__double2loint(v.y)),
                       __int_as_float(__double2loint(v.z)),
                       __int_as_float(__double2loint(v.w)));
}
__device__ __forceinline__ float4 hi4(const double4 v) {
    return make_float4(__int_as_float(__double2hiint(v.x)),
                       __int_as_float(__double2hiint(v.y)),
                       __int_as_float(__double2hiint(v.z)),
                       __int_as_float(__double2hiint(v.w)));
}
__device__ __forceinline__ double4 mk4(const float4 h, const float4 l) {
    return make_double4(__hiloint2double(__float_as_int(h.x), __float_as_int(l.x)),
                        __hiloint2double(__float_as_int(h.y), __float_as_int(l.y)),
                        __hiloint2double(__float_as_int(h.z), __float_as_int(l.z)),
                        __hiloint2double(__float_as_int(h.w), __float_as_int(l.w)));
}

__device__ __forceinline__ void t_fwd_d(float4* T4, double4* x, unsigned tid,
                                        unsigned lane, unsigned hi, bool protect) {
    if (protect) __syncthreads();
#pragma unroll
    for (int jj = 0; jj < 8; ++jj) T4[sw(tid | (jj << 9))] = lo4(x[jj]);
    __syncthreads();
    float4 tl[8];
#pragma unroll
    for (int jj = 0; jj < 8; ++jj) tl[jj] = T4[sw(lane | (jj << 6) | hi)];
    __syncthreads();
#pragma unroll
    for (int jj = 0; jj < 8; ++jj) T4[sw(tid | (jj << 9))] = hi4(x[jj]);
    __syncthreads();
#pragma unroll
    for (int jj = 0; jj < 8; ++jj)
        x[jj] = mk4(T4[sw(lane | (jj << 6) | hi)], tl[jj]);
}

__device__ __forceinline__ void t_back_d(float4* T4, double4* x, unsigned tid,
                                         unsigned lane, unsigned hi) {
    __syncthreads();
#pragma unroll
    for (int jj = 0; jj < 8; ++jj) T4[sw(lane | (jj << 6) | hi)] = lo4(x[jj]);
    __syncthreads();
    float4 tl[8];
#pragma unroll
    for (int jj = 0; jj < 8; ++jj) tl[jj] = T4[sw(tid | (jj << 9))];
    __syncthreads();
#pragma unroll
    for (int jj = 0; jj < 8; ++jj) T4[sw(lane | (jj << 6) | hi)] = hi4(x[jj]);
    __syncthreads();
#pragma unroll
    for (int jj = 0; jj < 8; ++jj)
        x[jj] = mk4(T4[sw(tid | (jj << 9))], tl[jj]);
}

// Three jj-space stages; start: 0=all three, 1=skip top, 2=only lowest.
__device__ __forceinline__ void jj_trio_d(double4* x, const double* c, const double* s,
                                          bool top_on, int start) {
    if (start == 0) {
        if (top_on) stage8d<2, 1>(x, c[0], s[0]);
        else        stage8d<2,-1>(x, c[0], s[0]);
    }
    if (start <= 1) stage8d<1, 0>(x, c[1], s[1]);
    stage8d<0, 0>(x, c[2], s[2]);
}

// Lane stages, masks 32..1 (targets lane bits 5..0); first ctrl = jj bit 0,
// rest ctrl = lane bit (target+1). n = how many from the top.
__device__ __forceinline__ void lane_ladder_d(double4* x, unsigned lane,
                                              const double* c, const double* s, int n) {
    {
        double cA0, cP0, cA1, cP1;
        coefs_d(lane, 5, false, c[0], s[0], cA0, cP0);
        coefs_d(lane, 5, true,  c[0], s[0], cA1, cP1);
        lane_stage_jc_d(x, 32, cA0, cP0, cA1, cP1);
    }
    if (n > 1) { double cA, cP; coefs_d(lane, 4, (lane >> 5) & 1, c[1], s[1], cA, cP); lane_stage_d(x, 16, cA, cP); }
    if (n > 2) { double cA, cP; coefs_d(lane, 3, (lane >> 4) & 1, c[2], s[2], cA, cP); lane_stage_d(x,  8, cA, cP); }
    if (n > 3) { double cA, cP; coefs_d(lane, 2, (lane >> 3) & 1, c[3], s[3], cA, cP); lane_stage_d(x,  4, cA, cP); }
    if (n > 4) { double cA, cP; coefs_d(lane, 1, (lane >> 2) & 1, c[4], s[4], cA, cP); lane_stage_d(x,  2, cA, cP); }
    if (n > 5) { double cA, cP; coefs_d(lane, 0, (lane >> 1) & 1, c[5], s[5], cA, cP); lane_stage_d(x,  1, cA, cP); }
}

__device__ __forceinline__ double4 d4_of(const float4 f) {
    return make_double4((double)f.x, (double)f.y, (double)f.z, (double)f.w);
}
__device__ __forceinline__ float4 f4_of(const double4 d) {
    return make_float4((float)d.x, (float)d.y, (float)d.z, (float)d.w);
}

// ---- H sweep: window bits {0,1} u {12..23}; m = global bits {2..11}.
// Block i (circuit block kbase+i) applies S23..S_{12+i}.
__global__ __launch_bounds__(512, 2) void k_H(float* __restrict__ st,
                                              const double* __restrict__ dws,
                                              int kbase, int nblk, int init) {
    __shared__ float4 T4[4096];   // 64 KB
    const unsigned bid = blockIdx.x;
    // XCD-contiguity swizzle: consecutive m (sharing 64B lines) -> same XCD.
    const unsigned m = (bid >> 3) | ((bid & 7u) << 7);
    const unsigned tid = threadIdx.x;
    const unsigned lane = tid & 63u;
    const unsigned hi = (tid >> 6) << 9;
    float4* G4 = reinterpret_cast<float4*>(st);
    double4 x[8];

    if (init) {
        // Block-0 analytic: amp(f) = prod_b phi_b(gray_b), gray = f ^ (f>>1).
        // f bits: f{0,1}=d; f{2..11}=m; f{12..20}=tid{0..8}; f{21..23}=jj.
        const double* C0 = dws + 8;
        const double* S0 = dws + 200;
        double P = 1.0;
#pragma unroll
        for (int b = 2; b <= 10; ++b) {
            unsigned g = ((m >> (b - 2)) ^ (m >> (b - 1))) & 1u;
            P *= g ? S0[23 - b] : C0[23 - b];
        }
        { unsigned g = ((m >> 9) ^ tid) & 1u; P *= g ? S0[12] : C0[12]; }   // b=11
#pragma unroll
        for (int b = 12; b <= 19; ++b) {
            unsigned g = ((tid >> (b - 12)) ^ (tid >> (b - 11))) & 1u;
            P *= g ? S0[23 - b] : C0[23 - b];
        }
        double D[4];
#pragma unroll
        for (int d = 0; d < 4; ++d) {
            unsigned g0 = (d ^ (d >> 1)) & 1u;
            unsigned g1 = ((d >> 1) ^ m) & 1u;
            D[d] = (g0 ? S0[23] : C0[23]) * (g1 ? S0[22] : C0[22]);
        }
        unsigned t8 = (tid >> 8) & 1u;
#pragma unroll
        for (int jj = 0; jj < 8; ++jj) {
            unsigned g20 = (t8 ^ (unsigned)jj) & 1u;
            unsigned g21 = ((unsigned)jj ^ ((unsigned)jj >> 1)) & 1u;
            unsigned g22 = (((unsigned)jj >> 1) ^ ((unsigned)jj >> 2)) & 1u;
            unsigned g23 = (((unsigned)jj >> 2)) & 1u;
            double J = (g20 ? S0[3] : C0[3]) * (g21 ? S0[2] : C0[2]) *
                       (g22 ? S0[1] : C0[1]) * (g23 ? S0[0] : C0[0]);
            double PJ = P * J;
            x[jj] = make_double4(PJ * D[0], PJ * D[1], PJ * D[2], PJ * D[3]);
        }
    } else {
#pragma unroll
        for (int jj = 0; jj < 8; ++jj) {
            unsigned w = tid | (jj << 9);
            x[jj] = d4_of(G4[m | (w << 10)]);
        }
    }

    for (int i = 0; i < nblk; ++i) {
        const double* C = dws + 8   + (kbase + i) * 24;
        const double* S = dws + 200 + (kbase + i) * 24;
        jj_trio_d(x, C + 0, S + 0, false, 0);               // S23 (RY only), S22, S21
        t_fwd_d(T4, x, tid, lane, hi, i > 0);
        jj_trio_d(x, C + 3, S + 3, (tid & 64u) != 0, 0);    // S20 (ctrl w9=tid6), S19, S18
        lane_ladder_d(x, lane, C + 6, S + 6, 6 - i);        // S17..S_{12+i}
        if (i < nblk - 1) t_back_d(T4, x, tid, lane, hi);
    }
    // store from layout2
#pragma unroll
    for (int jj = 0; jj < 8; ++jj) {
        unsigned w = lane | (jj << 6) | hi;
        G4[m | (w << 10)] = f4_of(x[jj]);
    }
}

// ---- L sweep: window bits {0..13}, contiguous; m = global bits {14..23}.
// Block i (circuit block kbase+i) applies S_{11+i}..S0.
__global__ __launch_bounds__(512, 2) void k_L(float* __restrict__ st,
                                              double* __restrict__ dws,
                                              int kbase, int nblk, int fuse) {
    __shared__ float4 T4[4096];   // 64 KB
    const unsigned m = blockIdx.x;
    const unsigned tid = threadIdx.x;
    const unsigned lane = tid & 63u;
    const unsigned hi = (tid >> 6) << 9;
    float4* G4 = reinterpret_cast<float4*>(st) + (m << 12);
    double4 x[8];
#pragma unroll
    for (int jj = 0; jj < 8; ++jj) x[jj] = d4_of(G4[tid + (jj << 9)]);

    for (int i = 0; i < nblk; ++i) {
        const double* C = dws + 8   + (kbase + i) * 24;
        const double* S = dws + 200 + (kbase + i) * 24;
        jj_trio_d(x, C + 10, S + 10, (m & 1u) != 0, 2 - i); // S13?, S12?, S11
        t_fwd_d(T4, x, tid, lane, hi, i > 0);
        jj_trio_d(x, C + 13, S + 13, (tid & 64u) != 0, 0);  // S10 (ctrl tid6), S9, S8
        lane_ladder_d(x, lane, C + 16, S + 16, 6);          // S7..S2
        dstages_d(x, C[22], S[22], lane & 1u, C[23], S[23]); // S1, S0
        if (i < nblk - 1) t_back_d(T4, x, tid, lane, hi);
    }

    if (fuse) {
        double lsum = 0.0;
#pragma unroll
        for (int jj = 0; jj < 8; ++jj) {
            double* v = &x[jj].x;
            float4 o;
            float* ov = &o.x;
#pragma unroll
            for (int d = 0; d < 4; ++d) {
                float z = (float)(838860.8 * v[d] * v[d]);
                float xf = xform(z);
                ov[d] = xf;
                lsum += (double)xf;
            }
            G4[lane | (jj << 6) | hi] = o;
        }
#pragma unroll
        for (int o = 32; o > 0; o >>= 1) lsum += __shfl_down(lsum, o, 64);
        __syncthreads();
        double* wsum = reinterpret_cast<double*>(T4);
        if ((tid & 63u) == 0) wsum[tid >> 6] = lsum;
        __syncthreads();
        if (tid == 0) {
            double b = 0.0;
#pragma unroll
            for (int i = 0; i < 8; ++i) b += wsum[i];
            atomicAdd(dws, b);
        }
    } else {
#pragma unroll
        for (int jj = 0; jj < 8; ++jj) G4[lane | (jj << 6) | hi] = f4_of(x[jj]);
    }
}

__global__ void k_final(float* __restrict__ st, const double* __restrict__ dws) {
    unsigned idx = blockIdx.x * blockDim.x + threadIdx.x;
    unsigned stride = gridDim.x * blockDim.x;
    float mean = (float)(dws[0] * (1.0 / 16777216.0));
    float4* G4 = reinterpret_cast<float4*>(st);
    for (unsigned q = idx; q < (SSIZE / 4); q += stride) {
        float4 v = G4[q];
        v.x -= mean; v.y -= mean; v.z -= mean; v.w -= mean;
        G4[q] = v;
    }
}

extern "C" void kernel_launch(void* const* d_in, const int* in_sizes, int n_in,
                              void* d_out, int out_size, void* d_ws, size_t ws_size,
                              hipStream_t stream) {
    const float* ang = (const float*)d_in[0];   // [8][24] float32
    float* st = (float*)d_out;                  // state in d_out, in place
    double* dws = (double*)d_ws;

    k_prep<<<1, 256, 0, stream>>>(ang, dws);
    // Light-cone fused schedule: blocks {1,2,3}, {4,5,6}, {7}; block 0 in init.
    k_H<<<1024, 512, 0, stream>>>(st, dws, 1, 3, 1);
    k_L<<<1024, 512, 0, stream>>>(st, dws, 1, 3, 0);
    k_H<<<1024, 512, 0, stream>>>(st, dws, 4, 3, 0);
    k_L<<<1024, 512, 0, stream>>>(st, dws, 4, 3, 0);
    k_H<<<1024, 512, 0, stream>>>(st, dws, 7, 1, 0);
    k_L<<<1024, 512, 0, stream>>>(st, dws, 7, 1, 1);
    k_final<<<4096, 256, 0, stream>>>(st, dws);
}

// Round 4
// 575.264 us; speedup vs baseline: 1.3208x; 1.3208x over previous
//
#include <hip/hip_runtime.h>

#define NB 8
#define SSIZE (1u << 24)

// Flat index convention (jnp reshape of (2,)*24): wire w <-> bit b = 23-w.
// Stage S_t = RY(bit t) + CNOT(ctrl bit t+1, tgt bit t), applied t = 23..0.
// Light-cone fused schedule (validated round 1/2), windows:
//   H = bits {0,1} u {12..23}  (block idx m = bits 2..11)
//   L = bits {0..13}           (block idx m = bits 14..23, contiguous 64KB)
// Per H+L pair THREE circuit blocks retire => 6 sweeps total.
//
// NUMERICS (validated round 2, absmax 0.0059 vs thr 0.0095): state evolves in
// fp64 registers in-kernel; global state between sweeps is fp32. LDS transposes
// exact (lo/hi word passes). Coefs/mean fp64.
//
// ROUND 4 (= round 3 intent, compile-fixed): lane-exchange stages off LDS onto
// VALU cross-lane ops (permlane32/16_swap pair trick, DPP row_ror:8, DPP
// quad_perm; only xor-4 keeps ds_swizzle). k_H block loop is now a recursive
// template h_block<I,NBLK> so lane_ladder_v<6-I> gets a constant argument.
//
// dws layout (doubles): [0]=sum, [8 + k*24 + w]=cos(theta/2), [200+...]=sin.

__global__ void k_prep(const float* __restrict__ ang, double* __restrict__ dws) {
    int t = threadIdx.x;
    if (t == 0) dws[0] = 0.0;
    if (t < NB * 24) {
        double a = 0.5 * (double)ang[t];
        dws[8 + t]   = cos(a);
        dws[200 + t] = sin(a);
    }
}

// ---- helpers ----------------------------------------------------------

__device__ __forceinline__ unsigned sw(unsigned f) {
    return f ^ (((f >> 3) ^ (f >> 5)) & 7u);
}

__device__ __forceinline__ void ry2d(double& a0, double& a1, double c, double s, bool ctl) {
    double w0 = c * a0 - s * a1;
    double w1 = s * a0 + c * a1;
    a0 = ctl ? w1 : w0;
    a1 = ctl ? w0 : w1;
}

// Stage on 8xdouble4 granule: elem bits {0,1}=d, {2,3,4}=register index jj.
template<int TB, int MODE>
__device__ __forceinline__ void stage8d(double4* x, double c, double s) {
#pragma unroll
    for (int j0 = 0; j0 < 8; ++j0) {
        if (j0 & (1 << TB)) continue;
        const int j1 = j0 | (1 << TB);
        const bool ctl = (MODE == 1) || (MODE == 0 && ((j0 >> (TB + 1)) & 1));
        ry2d(x[j0].x, x[j1].x, c, s, ctl);
        ry2d(x[j0].y, x[j1].y, c, s, ctl);
        ry2d(x[j0].z, x[j1].z, c, s, ctl);
        ry2d(x[j0].w, x[j1].w, c, s, ctl);
    }
}

__device__ __forceinline__ void coefs_d(unsigned lane, int lb, bool g,
                                        double c, double s, double& cA, double& cP) {
    bool b = (lane >> lb) & 1u;
    cA = g ? (b ? -s : s) : c;
    cP = g ? c : (b ? s : -s);
}

// ---- VALU cross-lane exchange machinery (exact, LDS-free) -------------

// DPP xor on a double (2x mov_dpp on 32b halves). CTRL: 0xB1=quad xor1,
// 0x4E=quad xor2, 0x128=row_ror:8 (== xor 8 within 16-lane row).
template<int CTRL>
__device__ __forceinline__ double dpp_xor_d(double v) {
    int lo = __builtin_amdgcn_mov_dpp(__double2loint(v), CTRL, 0xf, 0xf, true);
    int hi = __builtin_amdgcn_mov_dpp(__double2hiint(v), CTRL, 0xf, 0xf, true);
    return __hiloint2double(hi, lo);
}

template<int CTRL>
__device__ __forceinline__ void lane_stage_dpp(double4* x, double cA, double cP) {
#pragma unroll
    for (int j = 0; j < 8; ++j) {
        double px = dpp_xor_d<CTRL>(x[j].x);
        double py = dpp_xor_d<CTRL>(x[j].y);
        double pz = dpp_xor_d<CTRL>(x[j].z);
        double pw = dpp_xor_d<CTRL>(x[j].w);
        x[j].x = cA * x[j].x + cP * px;
        x[j].y = cA * x[j].y + cP * py;
        x[j].z = cA * x[j].z + cP * pz;
        x[j].w = cA * x[j].w + cP * pw;
    }
}

// ds_swizzle fallback for xor mask 4 (no DPP/permlane pattern).
__device__ __forceinline__ void lane_stage_sw4(double4* x, double cA, double cP) {
#pragma unroll
    for (int j = 0; j < 8; ++j) {
        double px = __shfl_xor(x[j].x, 4, 64);
        double py = __shfl_xor(x[j].y, 4, 64);
        double pz = __shfl_xor(x[j].z, 4, 64);
        double pw = __shfl_xor(x[j].w, 4, 64);
        x[j].x = cA * x[j].x + cP * px;
        x[j].y = cA * x[j].y + cP * py;
        x[j].z = cA * x[j].z + cP * pz;
        x[j].w = cA * x[j].w + cP * pw;
    }
}

// permlane swap on a double pair: word-wise. After swap32: A=[A_lo|B_lo],
// B=[A_hi|B_hi] -> each element's (bit5=0,bit5=1) components co-located in one
// lane; lanes<32 carry A-elements, lanes>=32 B-elements. Involution.
// permlane16_swap: same with 16-rows -> (bit4=0,bit4=1) co-located.
template<bool IS32>
__device__ __forceinline__ void swap_pair_d(double& a, double& b) {
    int alo = __double2loint(a), ahi = __double2hiint(a);
    int blo = __double2loint(b), bhi = __double2hiint(b);
    if (IS32) {
        auto r0 = __builtin_amdgcn_permlane32_swap(alo, blo, false, false);
        auto r1 = __builtin_amdgcn_permlane32_swap(ahi, bhi, false, false);
        alo = r0[0]; blo = r0[1]; ahi = r1[0]; bhi = r1[1];
    } else {
        auto r0 = __builtin_amdgcn_permlane16_swap(alo, blo, false, false);
        auto r1 = __builtin_amdgcn_permlane16_swap(ahi, bhi, false, false);
        alo = r0[0]; blo = r0[1]; ahi = r1[0]; bhi = r1[1];
    }
    a = __hiloint2double(ahi, alo);
    b = __hiloint2double(bhi, blo);
}

// Stage with target lane-bit5 (IS32) or bit4 (!IS32). In the swapped view the
// ctrl bit (jj0 for the bit5 stage, elem-bit5 for the bit4 stage) is lane>=32
// in BOTH cases. g? (al,be,ga,de)=(s,c,c,-s) : (c,-s,s,c).
template<bool IS32>
__device__ __forceinline__ void stage_swap(double4* x, double c, double s, bool gsel) {
    double al = gsel ? s : c, be = gsel ? c : -s;
    double ga = gsel ? c : s, de = gsel ? -s : c;
#pragma unroll
    for (int p = 0; p < 4; ++p) {
        double4& A = x[2 * p];
        double4& B = x[2 * p + 1];
        swap_pair_d<IS32>(A.x, B.x); swap_pair_d<IS32>(A.y, B.y);
        swap_pair_d<IS32>(A.z, B.z); swap_pair_d<IS32>(A.w, B.w);
        double ux = A.x, vx = B.x, uy = A.y, vy = B.y;
        double uz = A.z, vz = B.z, uw = A.w, vw = B.w;
        A.x = al * ux + be * vx;  B.x = ga * ux + de * vx;
        A.y = al * uy + be * vy;  B.y = ga * uy + de * vy;
        A.z = al * uz + be * vz;  B.z = ga * uz + de * vz;
        A.w = al * uw + be * vw;  B.w = ga * uw + de * vw;
        swap_pair_d<IS32>(A.x, B.x); swap_pair_d<IS32>(A.y, B.y);
        swap_pair_d<IS32>(A.z, B.z); swap_pair_d<IS32>(A.w, B.w);
    }
}

// S1 (tgt d1, ctrl = runtime bool g1) then S0 (tgt d0, ctrl d1).
__device__ __forceinline__ void dstages_d(double4* x, double c1, double s1, bool g1,
                                          double c0, double s0) {
#pragma unroll
    for (int j = 0; j < 8; ++j) {
        ry2d(x[j].x, x[j].z, c1, s1, g1);
        ry2d(x[j].y, x[j].w, c1, s1, g1);
        ry2d(x[j].x, x[j].y, c0, s0, false);
        ry2d(x[j].z, x[j].w, c0, s0, true);
    }
}

// x = (0.6*tanh(0.1*2^23*v^2))^0.15; small-z series avoids cancellation.
__device__ __forceinline__ float xform(float z) {
    float e2 = __builtin_amdgcn_exp2f(z * 2.8853900817779268f);   // e^(2z)
    float big = 1.0f - 2.0f * __builtin_amdgcn_rcpf(e2 + 1.0f);
    float z2 = z * z;
    float small_ = z * (1.0f - 0.33333333f * z2 * (1.0f - 0.4f * z2));
    float t = (z < 0.04f) ? small_ : big;
    return __builtin_amdgcn_exp2f(0.15f * __builtin_amdgcn_logf(0.6f * t));
}

// ---- exact fp64 LDS transposes (lo/hi word two-pass through 64KB tile) ---
// layout1: w = tid | (jj<<9)   layout2: w = lane | (jj<<6) | ((tid>>6)<<9)

__device__ __forceinline__ float4 lo4(const double4 v) {
    return make_float4(__int_as_float(__double2loint(v.x)),
                       __int_as_float(__double2loint(v.y)),
                       __int_as_float(__double2loint(v.z)),
                       __int_as_float(__double2loint(v.w)));
}
__device__ __forceinline__ float4 hi4(const double4 v) {
    return make_float4(__int_as_float(__double2hiint(v.x)),
                       __int_as_float(__double2hiint(v.y)),
                       __int_as_float(__double2hiint(v.z)),
                       __int_as_float(__double2hiint(v.w)));
}
__device__ __forceinline__ double4 mk4(const float4 h, const float4 l) {
    return make_double4(__hiloint2double(__float_as_int(h.x), __float_as_int(l.x)),
                        __hiloint2double(__float_as_int(h.y), __float_as_int(l.y)),
                        __hiloint2double(__float_as_int(h.z), __float_as_int(l.z)),
                        __hiloint2double(__float_as_int(h.w), __float_as_int(l.w)));
}

__device__ __forceinline__ void t_fwd_d(float4* T4, double4* x, unsigned tid,
                                        unsigned lane, unsigned hi, bool protect) {
    if (protect) __syncthreads();
#pragma unroll
    for (int jj = 0; jj < 8; ++jj) T4[sw(tid | (jj << 9))] = lo4(x[jj]);
    __syncthreads();
    float4 tl[8];
#pragma unroll
    for (int jj = 0; jj < 8; ++jj) tl[jj] = T4[sw(lane | (jj << 6) | hi)];
    __syncthreads();
#pragma unroll
    for (int jj = 0; jj < 8; ++jj) T4[sw(tid | (jj << 9))] = hi4(x[jj]);
    __syncthreads();
#pragma unroll
    for (int jj = 0; jj < 8; ++jj)
        x[jj] = mk4(T4[sw(lane | (jj << 6) | hi)], tl[jj]);
}

__device__ __forceinline__ void t_back_d(float4* T4, double4* x, unsigned tid,
                                         unsigned lane, unsigned hi) {
    __syncthreads();
#pragma unroll
    for (int jj = 0; jj < 8; ++jj) T4[sw(lane | (jj << 6) | hi)] = lo4(x[jj]);
    __syncthreads();
    float4 tl[8];
#pragma unroll
    for (int jj = 0; jj < 8; ++jj) tl[jj] = T4[sw(tid | (jj << 9))];
    __syncthreads();
#pragma unroll
    for (int jj = 0; jj < 8; ++jj) T4[sw(lane | (jj << 6) | hi)] = hi4(x[jj]);
    __syncthreads();
#pragma unroll
    for (int jj = 0; jj < 8; ++jj)
        x[jj] = mk4(T4[sw(tid | (jj << 9))], tl[jj]);
}

// Three jj-space stages; START: 0=all three, 1=skip top, 2=only lowest.
template<int START>
__device__ __forceinline__ void jj_trio_d(double4* x, const double* c, const double* s,
                                          bool top_on) {
    if (START == 0) {
        if (top_on) stage8d<2, 1>(x, c[0], s[0]);
        else        stage8d<2,-1>(x, c[0], s[0]);
    }
    if (START <= 1) stage8d<1, 0>(x, c[1], s[1]);
    stage8d<0, 0>(x, c[2], s[2]);
}

// Lane stages, targets lane bits 5..0; first ctrl = jj bit 0, rest ctrl = lane
// bit (target+1). N = how many from the top (4..6). VALU cross-lane except bit2.
template<int N>
__device__ __forceinline__ void lane_ladder_v(double4* x, unsigned lane,
                                              const double* c, const double* s) {
    const bool hi5 = lane >= 32;
    stage_swap<true>(x, c[0], s[0], hi5);                 // tgt bit5, ctrl jj0
    if (N > 1) stage_swap<false>(x, c[1], s[1], hi5);     // tgt bit4, ctrl bit5
    if (N > 2) { double cA, cP; coefs_d(lane, 3, (lane >> 4) & 1, c[2], s[2], cA, cP);
                 lane_stage_dpp<0x128>(x, cA, cP); }      // tgt bit3, row_ror:8
    if (N > 3) { double cA, cP; coefs_d(lane, 2, (lane >> 3) & 1, c[3], s[3], cA, cP);
                 lane_stage_sw4(x, cA, cP); }             // tgt bit2, ds_swizzle
    if (N > 4) { double cA, cP; coefs_d(lane, 1, (lane >> 2) & 1, c[4], s[4], cA, cP);
                 lane_stage_dpp<0x4E>(x, cA, cP); }       // tgt bit1, quad xor2
    if (N > 5) { double cA, cP; coefs_d(lane, 0, (lane >> 1) & 1, c[5], s[5], cA, cP);
                 lane_stage_dpp<0xB1>(x, cA, cP); }       // tgt bit0, quad xor1
}

__device__ __forceinline__ double4 d4_of(const float4 f) {
    return make_double4((double)f.x, (double)f.y, (double)f.z, (double)f.w);
}
__device__ __forceinline__ float4 f4_of(const double4 d) {
    return make_float4((float)d.x, (float)d.y, (float)d.z, (float)d.w);
}

// ---- H sweep block iteration, compile-time recursion over I -----------
// Block I (circuit block kbase+I) applies S23..S_{12+I}.
template<int I, int NBLK>
__device__ __forceinline__ void h_block(double4* x, float4* T4,
                                        const double* __restrict__ dws, int kbase,
                                        unsigned tid, unsigned lane, unsigned hi) {
    const double* C = dws + 8   + (kbase + I) * 24;
    const double* S = dws + 200 + (kbase + I) * 24;
    jj_trio_d<0>(x, C + 0, S + 0, false);               // S23 (RY only), S22, S21
    t_fwd_d(T4, x, tid, lane, hi, I > 0);
    jj_trio_d<0>(x, C + 3, S + 3, (tid & 64u) != 0);    // S20 (ctrl w9=tid6), S19, S18
    lane_ladder_v<6 - I>(x, lane, C + 6, S + 6);        // S17..S_{12+I}
    if constexpr (I < NBLK - 1) {
        t_back_d(T4, x, tid, lane, hi);
        h_block<I + 1, NBLK>(x, T4, dws, kbase, tid, lane, hi);
    }
}

// ---- H sweep: window bits {0,1} u {12..23}; m = global bits {2..11}.
template<int NBLK, int INIT>
__global__ __launch_bounds__(512, 2) void k_H(float* __restrict__ st,
                                              const double* __restrict__ dws,
                                              int kbase) {
    __shared__ float4 T4[4096];   // 64 KB
    const unsigned bid = blockIdx.x;
    // XCD-contiguity swizzle: each XCD gets a contiguous m-range.
    const unsigned m = (bid >> 3) | ((bid & 7u) << 7);
    const unsigned tid = threadIdx.x;
    const unsigned lane = tid & 63u;
    const unsigned hi = (tid >> 6) << 9;
    float4* G4 = reinterpret_cast<float4*>(st);
    double4 x[8];

    if (INIT) {
        // Block-0 analytic: amp(f) = prod_b phi_b(gray_b), gray = f ^ (f>>1).
        // f bits: f{0,1}=d; f{2..11}=m; f{12..20}=tid{0..8}; f{21..23}=jj.
        const double* C0 = dws + 8;
        const double* S0 = dws + 200;
        double P = 1.0;
#pragma unroll
        for (int b = 2; b <= 10; ++b) {
            unsigned g = ((m >> (b - 2)) ^ (m >> (b - 1))) & 1u;
            P *= g ? S0[23 - b] : C0[23 - b];
        }
        { unsigned g = ((m >> 9) ^ tid) & 1u; P *= g ? S0[12] : C0[12]; }   // b=11
#pragma unroll
        for (int b = 12; b <= 19; ++b) {
            unsigned g = ((tid >> (b - 12)) ^ (tid >> (b - 11))) & 1u;
            P *= g ? S0[23 - b] : C0[23 - b];
        }
        double D[4];
#pragma unroll
        for (int d = 0; d < 4; ++d) {
            unsigned g0 = (d ^ (d >> 1)) & 1u;
            unsigned g1 = ((d >> 1) ^ m) & 1u;
            D[d] = (g0 ? S0[23] : C0[23]) * (g1 ? S0[22] : C0[22]);
        }
        unsigned t8 = (tid >> 8) & 1u;
#pragma unroll
        for (int jj = 0; jj < 8; ++jj) {
            unsigned g20 = (t8 ^ (unsigned)jj) & 1u;
            unsigned g21 = ((unsigned)jj ^ ((unsigned)jj >> 1)) & 1u;
            unsigned g22 = (((unsigned)jj >> 1) ^ ((unsigned)jj >> 2)) & 1u;
            unsigned g23 = (((unsigned)jj >> 2)) & 1u;
            double J = (g20 ? S0[3] : C0[3]) * (g21 ? S0[2] : C0[2]) *
                       (g22 ? S0[1] : C0[1]) * (g23 ? S0[0] : C0[0]);
            double PJ = P * J;
            x[jj] = make_double4(PJ * D[0], PJ * D[1], PJ * D[2], PJ * D[3]);
        }
    } else {
#pragma unroll
        for (int jj = 0; jj < 8; ++jj) {
            unsigned w = tid | (jj << 9);
            x[jj] = d4_of(G4[m | (w << 10)]);
        }
    }

    h_block<0, NBLK>(x, T4, dws, kbase, tid, lane, hi);

    // store from layout2
#pragma unroll
    for (int jj = 0; jj < 8; ++jj) {
        unsigned w = lane | (jj << 6) | hi;
        G4[m | (w << 10)] = f4_of(x[jj]);
    }
}

// ---- L sweep: window bits {0..13}, contiguous; m = global bits {14..23}.
// Block i (circuit block kbase+i) applies S_{11+i}..S0.
template<int NBLK, int FUSE>
__global__ __launch_bounds__(512, 2) void k_L(float* __restrict__ st,
                                              double* __restrict__ dws,
                                              int kbase) {
    __shared__ float4 T4[4096];   // 64 KB
    const unsigned m = blockIdx.x;
    const unsigned tid = threadIdx.x;
    const unsigned lane = tid & 63u;
    const unsigned hi = (tid >> 6) << 9;
    float4* G4 = reinterpret_cast<float4*>(st) + (m << 12);
    double4 x[8];
#pragma unroll
    for (int jj = 0; jj < 8; ++jj) x[jj] = d4_of(G4[tid + (jj << 9)]);

#pragma unroll
    for (int i = 0; i < NBLK; ++i) {
        const double* C = dws + 8   + (kbase + i) * 24;
        const double* S = dws + 200 + (kbase + i) * 24;
        // S13 (ctrl = bit14 = m&1, i>=2), S12 (i>=1), S11
        if (i == 0)      jj_trio_d<2>(x, C + 10, S + 10, false);
        else if (i == 1) jj_trio_d<1>(x, C + 10, S + 10, false);
        else             jj_trio_d<0>(x, C + 10, S + 10, (m & 1u) != 0);
        t_fwd_d(T4, x, tid, lane, hi, i > 0);
        jj_trio_d<0>(x, C + 13, S + 13, (tid & 64u) != 0);  // S10 (ctrl tid6), S9, S8
        lane_ladder_v<6>(x, lane, C + 16, S + 16);          // S7..S2
        dstages_d(x, C[22], S[22], lane & 1u, C[23], S[23]); // S1, S0
        if (i < NBLK - 1) t_back_d(T4, x, tid, lane, hi);
    }

    if (FUSE) {
        double lsum = 0.0;
#pragma unroll
        for (int jj = 0; jj < 8; ++jj) {
            double* v = &x[jj].x;
            float4 o;
            float* ov = &o.x;
#pragma unroll
            for (int d = 0; d < 4; ++d) {
                float z = (float)(838860.8 * v[d] * v[d]);
                float xf = xform(z);
                ov[d] = xf;
                lsum += (double)xf;
            }
            G4[lane | (jj << 6) | hi] = o;
        }
#pragma unroll
        for (int o = 32; o > 0; o >>= 1) lsum += __shfl_down(lsum, o, 64);
        __syncthreads();
        double* wsum = reinterpret_cast<double*>(T4);
        if ((tid & 63u) == 0) wsum[tid >> 6] = lsum;
        __syncthreads();
        if (tid == 0) {
            double b = 0.0;
#pragma unroll
            for (int i = 0; i < 8; ++i) b += wsum[i];
            atomicAdd(dws, b);
        }
    } else {
#pragma unroll
        for (int jj = 0; jj < 8; ++jj) G4[lane | (jj << 6) | hi] = f4_of(x[jj]);
    }
}

__global__ void k_final(float* __restrict__ st, const double* __restrict__ dws) {
    unsigned idx = blockIdx.x * blockDim.x + threadIdx.x;
    unsigned stride = gridDim.x * blockDim.x;
    float mean = (float)(dws[0] * (1.0 / 16777216.0));
    float4* G4 = reinterpret_cast<float4*>(st);
    for (unsigned q = idx; q < (SSIZE / 4); q += stride) {
        float4 v = G4[q];
        v.x -= mean; v.y -= mean; v.z -= mean; v.w -= mean;
        G4[q] = v;
    }
}

extern "C" void kernel_launch(void* const* d_in, const int* in_sizes, int n_in,
                              void* d_out, int out_size, void* d_ws, size_t ws_size,
                              hipStream_t stream) {
    const float* ang = (const float*)d_in[0];   // [8][24] float32
    float* st = (float*)d_out;                  // state in d_out, in place
    double* dws = (double*)d_ws;

    k_prep<<<1, 256, 0, stream>>>(ang, dws);
    // Light-cone fused schedule: blocks {1,2,3}, {4,5,6}, {7}; block 0 in init.
    k_H<3, 1><<<1024, 512, 0, stream>>>(st, dws, 1);
    k_L<3, 0><<<1024, 512, 0, stream>>>(st, dws, 1);
    k_H<3, 0><<<1024, 512, 0, stream>>>(st, dws, 4);
    k_L<3, 0><<<1024, 512, 0, stream>>>(st, dws, 4);
    k_H<1, 0><<<1024, 512, 0, stream>>>(st, dws, 7);
    k_L<1, 1><<<1024, 512, 0, stream>>>(st, dws, 7);
    k_final<<<4096, 256, 0, stream>>>(st, dws);
}

// Round 5
// 568.454 us; speedup vs baseline: 1.3366x; 1.0120x over previous
//
#include <hip/hip_runtime.h>

#define NB 8
#define SSIZE (1u << 24)

// Flat index convention (jnp reshape of (2,)*24): wire w <-> bit b = 23-w.
// Stage S_t = RY(bit t) + CNOT(ctrl bit t+1, tgt bit t), applied t = 23..0.
// Light-cone fused schedule (validated r1/r2), windows:
//   H = bits {0,1} u {12..23}  (block idx m = bits 2..11)
//   L = bits {0..13}           (block idx m = bits 14..23)
// Per H+L pair THREE circuit blocks retire => 6 sweeps total.
//
// NUMERICS (validated r2/r4, absmax 0.00586 vs thr 0.00953): state evolves in
// fp64 registers in-kernel; global state between sweeps is fp32. LDS transposes
// exact (lo/hi word passes). Coefs/mean fp64.
//
// ROUND 5: intermediate sweeps stored in a PERMUTED global layout pi that
// swaps f{2,3} <-> f{12,13} in the float4-address:
//   addr4 bits = [0,1]=f12,f13 | [2..9]=f4..f11 | [10,11]=f2,f3 | [12..21]=f14..f23
// => k_H tiles become 64B-contiguous granules (16 lines/wave vs 64 before);
//    k_L tiles stay exactly 64KB contiguous (lane order shuffles only).
// Final fused store writes TRUE layout (low-14-bit window is contiguous there).
//
// dws layout (doubles): [0]=sum, [8 + k*24 + w]=cos(theta/2), [200+...]=sin.

__global__ void k_prep(const float* __restrict__ ang, double* __restrict__ dws) {
    int t = threadIdx.x;
    if (t == 0) dws[0] = 0.0;
    if (t < NB * 24) {
        double a = 0.5 * (double)ang[t];
        dws[8 + t]   = cos(a);
        dws[200 + t] = sin(a);
    }
}

// ---- helpers ----------------------------------------------------------

__device__ __forceinline__ unsigned sw(unsigned f) {
    return f ^ (((f >> 3) ^ (f >> 5)) & 7u);
}

__device__ __forceinline__ void ry2d(double& a0, double& a1, double c, double s, bool ctl) {
    double w0 = c * a0 - s * a1;
    double w1 = s * a0 + c * a1;
    a0 = ctl ? w1 : w0;
    a1 = ctl ? w0 : w1;
}

// Stage on 8xdouble4 granule: elem bits {0,1}=d, {2,3,4}=register index jj.
template<int TB, int MODE>
__device__ __forceinline__ void stage8d(double4* x, double c, double s) {
#pragma unroll
    for (int j0 = 0; j0 < 8; ++j0) {
        if (j0 & (1 << TB)) continue;
        const int j1 = j0 | (1 << TB);
        const bool ctl = (MODE == 1) || (MODE == 0 && ((j0 >> (TB + 1)) & 1));
        ry2d(x[j0].x, x[j1].x, c, s, ctl);
        ry2d(x[j0].y, x[j1].y, c, s, ctl);
        ry2d(x[j0].z, x[j1].z, c, s, ctl);
        ry2d(x[j0].w, x[j1].w, c, s, ctl);
    }
}

__device__ __forceinline__ void coefs_d(unsigned lane, int lb, bool g,
                                        double c, double s, double& cA, double& cP) {
    bool b = (lane >> lb) & 1u;
    cA = g ? (b ? -s : s) : c;
    cP = g ? c : (b ? s : -s);
}

// ---- VALU cross-lane exchange machinery (exact, LDS-free) -------------

// DPP xor on a double (2x mov_dpp on 32b halves). CTRL: 0xB1=quad xor1,
// 0x4E=quad xor2, 0x128=row_ror:8 (== xor 8 within 16-lane row).
template<int CTRL>
__device__ __forceinline__ double dpp_xor_d(double v) {
    int lo = __builtin_amdgcn_mov_dpp(__double2loint(v), CTRL, 0xf, 0xf, true);
    int hi = __builtin_amdgcn_mov_dpp(__double2hiint(v), CTRL, 0xf, 0xf, true);
    return __hiloint2double(hi, lo);
}

template<int CTRL>
__device__ __forceinline__ void lane_stage_dpp(double4* x, double cA, double cP) {
#pragma unroll
    for (int j = 0; j < 8; ++j) {
        double px = dpp_xor_d<CTRL>(x[j].x);
        double py = dpp_xor_d<CTRL>(x[j].y);
        double pz = dpp_xor_d<CTRL>(x[j].z);
        double pw = dpp_xor_d<CTRL>(x[j].w);
        x[j].x = cA * x[j].x + cP * px;
        x[j].y = cA * x[j].y + cP * py;
        x[j].z = cA * x[j].z + cP * pz;
        x[j].w = cA * x[j].w + cP * pw;
    }
}

// ds_swizzle fallback for xor mask 4 (no DPP/permlane pattern).
__device__ __forceinline__ void lane_stage_sw4(double4* x, double cA, double cP) {
#pragma unroll
    for (int j = 0; j < 8; ++j) {
        double px = __shfl_xor(x[j].x, 4, 64);
        double py = __shfl_xor(x[j].y, 4, 64);
        double pz = __shfl_xor(x[j].z, 4, 64);
        double pw = __shfl_xor(x[j].w, 4, 64);
        x[j].x = cA * x[j].x + cP * px;
        x[j].y = cA * x[j].y + cP * py;
        x[j].z = cA * x[j].z + cP * pz;
        x[j].w = cA * x[j].w + cP * pw;
    }
}

// permlane swap on a double pair: word-wise. After swap32: A=[A_lo|B_lo],
// B=[A_hi|B_hi] -> each element's (bit5=0,bit5=1) components co-located in one
// lane; lanes<32 carry A-elements, lanes>=32 B-elements. Involution.
// permlane16_swap: same with 16-rows -> (bit4=0,bit4=1) co-located.
template<bool IS32>
__device__ __forceinline__ void swap_pair_d(double& a, double& b) {
    int alo = __double2loint(a), ahi = __double2hiint(a);
    int blo = __double2loint(b), bhi = __double2hiint(b);
    if (IS32) {
        auto r0 = __builtin_amdgcn_permlane32_swap(alo, blo, false, false);
        auto r1 = __builtin_amdgcn_permlane32_swap(ahi, bhi, false, false);
        alo = r0[0]; blo = r0[1]; ahi = r1[0]; bhi = r1[1];
    } else {
        auto r0 = __builtin_amdgcn_permlane16_swap(alo, blo, false, false);
        auto r1 = __builtin_amdgcn_permlane16_swap(ahi, bhi, false, false);
        alo = r0[0]; blo = r0[1]; ahi = r1[0]; bhi = r1[1];
    }
    a = __hiloint2double(ahi, alo);
    b = __hiloint2double(bhi, blo);
}

// Stage with target lane-bit5 (IS32) or bit4 (!IS32). In the swapped view the
// ctrl bit (jj0 for the bit5 stage, elem-bit5 for the bit4 stage) is lane>=32
// in BOTH cases. g? (al,be,ga,de)=(s,c,c,-s) : (c,-s,s,c).
template<bool IS32>
__device__ __forceinline__ void stage_swap(double4* x, double c, double s, bool gsel) {
    double al = gsel ? s : c, be = gsel ? c : -s;
    double ga = gsel ? c : s, de = gsel ? -s : c;
#pragma unroll
    for (int p = 0; p < 4; ++p) {
        double4& A = x[2 * p];
        double4& B = x[2 * p + 1];
        swap_pair_d<IS32>(A.x, B.x); swap_pair_d<IS32>(A.y, B.y);
        swap_pair_d<IS32>(A.z, B.z); swap_pair_d<IS32>(A.w, B.w);
        double ux = A.x, vx = B.x, uy = A.y, vy = B.y;
        double uz = A.z, vz = B.z, uw = A.w, vw = B.w;
        A.x = al * ux + be * vx;  B.x = ga * ux + de * vx;
        A.y = al * uy + be * vy;  B.y = ga * uy + de * vy;
        A.z = al * uz + be * vz;  B.z = ga * uz + de * vz;
        A.w = al * uw + be * vw;  B.w = ga * uw + de * vw;
        swap_pair_d<IS32>(A.x, B.x); swap_pair_d<IS32>(A.y, B.y);
        swap_pair_d<IS32>(A.z, B.z); swap_pair_d<IS32>(A.w, B.w);
    }
}

// S1 (tgt d1, ctrl = runtime bool g1) then S0 (tgt d0, ctrl d1).
__device__ __forceinline__ void dstages_d(double4* x, double c1, double s1, bool g1,
                                          double c0, double s0) {
#pragma unroll
    for (int j = 0; j < 8; ++j) {
        ry2d(x[j].x, x[j].z, c1, s1, g1);
        ry2d(x[j].y, x[j].w, c1, s1, g1);
        ry2d(x[j].x, x[j].y, c0, s0, false);
        ry2d(x[j].z, x[j].w, c0, s0, true);
    }
}

// x = (0.6*tanh(0.1*2^23*v^2))^0.15; small-z series avoids cancellation.
__device__ __forceinline__ float xform(float z) {
    float e2 = __builtin_amdgcn_exp2f(z * 2.8853900817779268f);   // e^(2z)
    float big = 1.0f - 2.0f * __builtin_amdgcn_rcpf(e2 + 1.0f);
    float z2 = z * z;
    float small_ = z * (1.0f - 0.33333333f * z2 * (1.0f - 0.4f * z2));
    float t = (z < 0.04f) ? small_ : big;
    return __builtin_amdgcn_exp2f(0.15f * __builtin_amdgcn_logf(0.6f * t));
}

// ---- exact fp64 LDS transposes (lo/hi word two-pass through 64KB tile) ---
// layout1: w = tid | (jj<<9)   layout2: w = lane | (jj<<6) | ((tid>>6)<<9)

__device__ __forceinline__ float4 lo4(const double4 v) {
    return make_float4(__int_as_float(__double2loint(v.x)),
                       __int_as_float(__double2loint(v.y)),
                       __int_as_float(__double2loint(v.z)),
                       __int_as_float(__double2loint(v.w)));
}
__device__ __forceinline__ float4 hi4(const double4 v) {
    return make_float4(__int_as_float(__double2hiint(v.x)),
                       __int_as_float(__double2hiint(v.y)),
                       __int_as_float(__double2hiint(v.z)),
                       __int_as_float(__double2hiint(v.w)));
}
__device__ __forceinline__ double4 mk4(const float4 h, const float4 l) {
    return make_double4(__hiloint2double(__float_as_int(h.x), __float_as_int(l.x)),
                        __hiloint2double(__float_as_int(h.y), __float_as_int(l.y)),
                        __hiloint2double(__float_as_int(h.z), __float_as_int(l.z)),
                        __hiloint2double(__float_as_int(h.w), __float_as_int(l.w)));
}

__device__ __forceinline__ void t_fwd_d(float4* T4, double4* x, unsigned tid,
                                        unsigned lane, unsigned hi, bool protect) {
    if (protect) __syncthreads();
#pragma unroll
    for (int jj = 0; jj < 8; ++jj) T4[sw(tid | (jj << 9))] = lo4(x[jj]);
    __syncthreads();
    float4 tl[8];
#pragma unroll
    for (int jj = 0; jj < 8; ++jj) tl[jj] = T4[sw(lane | (jj << 6) | hi)];
    __syncthreads();
#pragma unroll
    for (int jj = 0; jj < 8; ++jj) T4[sw(tid | (jj << 9))] = hi4(x[jj]);
    __syncthreads();
#pragma unroll
    for (int jj = 0; jj < 8; ++jj)
        x[jj] = mk4(T4[sw(lane | (jj << 6) | hi)], tl[jj]);
}

__device__ __forceinline__ void t_back_d(float4* T4, double4* x, unsigned tid,
                                         unsigned lane, unsigned hi) {
    __syncthreads();
#pragma unroll
    for (int jj = 0; jj < 8; ++jj) T4[sw(lane | (jj << 6) | hi)] = lo4(x[jj]);
    __syncthreads();
    float4 tl[8];
#pragma unroll
    for (int jj = 0; jj < 8; ++jj) tl[jj] = T4[sw(tid | (jj << 9))];
    __syncthreads();
#pragma unroll
    for (int jj = 0; jj < 8; ++jj) T4[sw(lane | (jj << 6) | hi)] = hi4(x[jj]);
    __syncthreads();
#pragma unroll
    for (int jj = 0; jj < 8; ++jj)
        x[jj] = mk4(T4[sw(tid | (jj << 9))], tl[jj]);
}

// Three jj-space stages; START: 0=all three, 1=skip top, 2=only lowest.
template<int START>
__device__ __forceinline__ void jj_trio_d(double4* x, const double* c, const double* s,
                                          bool top_on) {
    if (START == 0) {
        if (top_on) stage8d<2, 1>(x, c[0], s[0]);
        else        stage8d<2,-1>(x, c[0], s[0]);
    }
    if (START <= 1) stage8d<1, 0>(x, c[1], s[1]);
    stage8d<0, 0>(x, c[2], s[2]);
}

// Lane stages, targets lane bits 5..0; first ctrl = jj bit 0, rest ctrl = lane
// bit (target+1). N = how many from the top (4..6). VALU cross-lane except bit2.
template<int N>
__device__ __forceinline__ void lane_ladder_v(double4* x, unsigned lane,
                                              const double* c, const double* s) {
    const bool hi5 = lane >= 32;
    stage_swap<true>(x, c[0], s[0], hi5);                 // tgt bit5, ctrl jj0
    if (N > 1) stage_swap<false>(x, c[1], s[1], hi5);     // tgt bit4, ctrl bit5
    if (N > 2) { double cA, cP; coefs_d(lane, 3, (lane >> 4) & 1, c[2], s[2], cA, cP);
                 lane_stage_dpp<0x128>(x, cA, cP); }      // tgt bit3, row_ror:8
    if (N > 3) { double cA, cP; coefs_d(lane, 2, (lane >> 3) & 1, c[3], s[3], cA, cP);
                 lane_stage_sw4(x, cA, cP); }             // tgt bit2, ds_swizzle
    if (N > 4) { double cA, cP; coefs_d(lane, 1, (lane >> 2) & 1, c[4], s[4], cA, cP);
                 lane_stage_dpp<0x4E>(x, cA, cP); }       // tgt bit1, quad xor2
    if (N > 5) { double cA, cP; coefs_d(lane, 0, (lane >> 1) & 1, c[5], s[5], cA, cP);
                 lane_stage_dpp<0xB1>(x, cA, cP); }       // tgt bit0, quad xor1
}

__device__ __forceinline__ double4 d4_of(const float4 f) {
    return make_double4((double)f.x, (double)f.y, (double)f.z, (double)f.w);
}
__device__ __forceinline__ float4 f4_of(const double4 d) {
    return make_float4((float)d.x, (float)d.y, (float)d.z, (float)d.w);
}

// ---- H sweep block iteration, compile-time recursion over I -----------
// Block I (circuit block kbase+I) applies S23..S_{12+I}.
template<int I, int NBLK>
__device__ __forceinline__ void h_block(double4* x, float4* T4,
                                        const double* __restrict__ dws, int kbase,
                                        unsigned tid, unsigned lane, unsigned hi) {
    const double* C = dws + 8   + (kbase + I) * 24;
    const double* S = dws + 200 + (kbase + I) * 24;
    jj_trio_d<0>(x, C + 0, S + 0, false);               // S23 (RY only), S22, S21
    t_fwd_d(T4, x, tid, lane, hi, I > 0);
    jj_trio_d<0>(x, C + 3, S + 3, (tid & 64u) != 0);    // S20 (ctrl w9=tid6), S19, S18
    lane_ladder_v<6 - I>(x, lane, C + 6, S + 6);        // S17..S_{12+I}
    if constexpr (I < NBLK - 1) {
        t_back_d(T4, x, tid, lane, hi);
        h_block<I + 1, NBLK>(x, T4, dws, kbase, tid, lane, hi);
    }
}

// ---- H sweep: window bits {0,1} u {12..23}; m = global bits {2..11}.
// pi-layout addr4: mbase = f2,f3 at bits 10,11 and f4..f11 at bits 2..9;
// window: w&3 (f12,f13) at bits 0,1; w>>2 (f14..f23) at bits 12..21.
// => 64B-contiguous granules per 4 lanes.
template<int NBLK, int INIT>
__global__ __launch_bounds__(512, 2) void k_H(float* __restrict__ st,
                                              const double* __restrict__ dws,
                                              int kbase) {
    __shared__ float4 T4[4096];   // 64 KB
    const unsigned bid = blockIdx.x;
    // XCD-contiguity swizzle: each XCD gets a contiguous m-range.
    const unsigned m = (bid >> 3) | ((bid & 7u) << 7);
    const unsigned tid = threadIdx.x;
    const unsigned lane = tid & 63u;
    const unsigned hi = (tid >> 6) << 9;
    const unsigned mbase4 = ((m & 3u) << 10) | ((m >> 2) << 2);
    float4* G4 = reinterpret_cast<float4*>(st);
    double4 x[8];

    if (INIT) {
        // Block-0 analytic: amp(f) = prod_b phi_b(gray_b), gray = f ^ (f>>1).
        // f bits: f{0,1}=d; f{2..11}=m; f{12..20}=tid{0..8}; f{21..23}=jj.
        const double* C0 = dws + 8;
        const double* S0 = dws + 200;
        double P = 1.0;
#pragma unroll
        for (int b = 2; b <= 10; ++b) {
            unsigned g = ((m >> (b - 2)) ^ (m >> (b - 1))) & 1u;
            P *= g ? S0[23 - b] : C0[23 - b];
        }
        { unsigned g = ((m >> 9) ^ tid) & 1u; P *= g ? S0[12] : C0[12]; }   // b=11
#pragma unroll
        for (int b = 12; b <= 19; ++b) {
            unsigned g = ((tid >> (b - 12)) ^ (tid >> (b - 11))) & 1u;
            P *= g ? S0[23 - b] : C0[23 - b];
        }
        double D[4];
#pragma unroll
        for (int d = 0; d < 4; ++d) {
            unsigned g0 = (d ^ (d >> 1)) & 1u;
            unsigned g1 = ((d >> 1) ^ m) & 1u;
            D[d] = (g0 ? S0[23] : C0[23]) * (g1 ? S0[22] : C0[22]);
        }
        unsigned t8 = (tid >> 8) & 1u;
#pragma unroll
        for (int jj = 0; jj < 8; ++jj) {
            unsigned g20 = (t8 ^ (unsigned)jj) & 1u;
            unsigned g21 = ((unsigned)jj ^ ((unsigned)jj >> 1)) & 1u;
            unsigned g22 = (((unsigned)jj >> 1) ^ ((unsigned)jj >> 2)) & 1u;
            unsigned g23 = (((unsigned)jj >> 2)) & 1u;
            double J = (g20 ? S0[3] : C0[3]) * (g21 ? S0[2] : C0[2]) *
                       (g22 ? S0[1] : C0[1]) * (g23 ? S0[0] : C0[0]);
            double PJ = P * J;
            x[jj] = make_double4(PJ * D[0], PJ * D[1], PJ * D[2], PJ * D[3]);
        }
    } else {
#pragma unroll
        for (int jj = 0; jj < 8; ++jj) {
            unsigned w = tid | (jj << 9);
            x[jj] = d4_of(G4[mbase4 | (w & 3u) | ((w >> 2) << 12)]);
        }
    }

    h_block<0, NBLK>(x, T4, dws, kbase, tid, lane, hi);

    // store from layout2 (pi-layout)
#pragma unroll
    for (int jj = 0; jj < 8; ++jj) {
        unsigned w = lane | (jj << 6) | hi;
        G4[mbase4 | (w & 3u) | ((w >> 2) << 12)] = f4_of(x[jj]);
    }
}

// ---- L sweep: window bits {0..13}; m = global bits {14..23}.
// pi-layout: tile is still the contiguous 64KB chunk [m<<12 .. m<<12+4095] in
// float4 space; local f4-index lf (bit i = f_{i+2}) maps to
//   a4(lf) = ((lf>>10)&3) | (((lf>>2)&0xFF)<<2) | ((lf&3)<<10).
// Block i (circuit block kbase+i) applies S_{11+i}..S0.
template<int NBLK, int FUSE>
__global__ __launch_bounds__(512, 2) void k_L(float* __restrict__ st,
                                              double* __restrict__ dws,
                                              int kbase) {
    __shared__ float4 T4[4096];   // 64 KB
    const unsigned m = blockIdx.x;
    const unsigned tid = threadIdx.x;
    const unsigned lane = tid & 63u;
    const unsigned hi = (tid >> 6) << 9;
    float4* G4 = reinterpret_cast<float4*>(st) + (m << 12);
    double4 x[8];
#pragma unroll
    for (int jj = 0; jj < 8; ++jj) {
        unsigned lf = tid | (jj << 9);
        unsigned a4 = ((lf >> 10) & 3u) | (((lf >> 2) & 0xFFu) << 2) | ((lf & 3u) << 10);
        x[jj] = d4_of(G4[a4]);
    }

#pragma unroll
    for (int i = 0; i < NBLK; ++i) {
        const double* C = dws + 8   + (kbase + i) * 24;
        const double* S = dws + 200 + (kbase + i) * 24;
        // S13 (ctrl = bit14 = m&1, i>=2), S12 (i>=1), S11
        if (i == 0)      jj_trio_d<2>(x, C + 10, S + 10, false);
        else if (i == 1) jj_trio_d<1>(x, C + 10, S + 10, false);
        else             jj_trio_d<0>(x, C + 10, S + 10, (m & 1u) != 0);
        t_fwd_d(T4, x, tid, lane, hi, i > 0);
        jj_trio_d<0>(x, C + 13, S + 13, (tid & 64u) != 0);  // S10 (ctrl tid6), S9, S8
        lane_ladder_v<6>(x, lane, C + 16, S + 16);          // S7..S2
        dstages_d(x, C[22], S[22], lane & 1u, C[23], S[23]); // S1, S0
        if (i < NBLK - 1) t_back_d(T4, x, tid, lane, hi);
    }

    if (FUSE) {
        // FINAL output: TRUE layout (contiguous for this window) + transform.
        double lsum = 0.0;
#pragma unroll
        for (int jj = 0; jj < 8; ++jj) {
            double* v = &x[jj].x;
            float4 o;
            float* ov = &o.x;
#pragma unroll
            for (int d = 0; d < 4; ++d) {
                float z = (float)(838860.8 * v[d] * v[d]);
                float xf = xform(z);
                ov[d] = xf;
                lsum += (double)xf;
            }
            G4[lane | (jj << 6) | hi] = o;
        }
#pragma unroll
        for (int o = 32; o > 0; o >>= 1) lsum += __shfl_down(lsum, o, 64);
        __syncthreads();
        double* wsum = reinterpret_cast<double*>(T4);
        if ((tid & 63u) == 0) wsum[tid >> 6] = lsum;
        __syncthreads();
        if (tid == 0) {
            double b = 0.0;
#pragma unroll
            for (int i = 0; i < 8; ++i) b += wsum[i];
            atomicAdd(dws, b);
        }
    } else {
        // pi-layout store from layout2
#pragma unroll
        for (int jj = 0; jj < 8; ++jj) {
            unsigned lf = lane | (jj << 6) | hi;
            unsigned a4 = ((lf >> 10) & 3u) | (((lf >> 2) & 0xFFu) << 2) | ((lf & 3u) << 10);
            G4[a4] = f4_of(x[jj]);
        }
    }
}

__global__ void k_final(float* __restrict__ st, const double* __restrict__ dws) {
    unsigned idx = blockIdx.x * blockDim.x + threadIdx.x;
    unsigned stride = gridDim.x * blockDim.x;
    float mean = (float)(dws[0] * (1.0 / 16777216.0));
    float4* G4 = reinterpret_cast<float4*>(st);
    for (unsigned q = idx; q < (SSIZE / 4); q += stride) {
        float4 v = G4[q];
        v.x -= mean; v.y -= mean; v.z -= mean; v.w -= mean;
        G4[q] = v;
    }
}

extern "C" void kernel_launch(void* const* d_in, const int* in_sizes, int n_in,
                              void* d_out, int out_size, void* d_ws, size_t ws_size,
                              hipStream_t stream) {
    const float* ang = (const float*)d_in[0];   // [8][24] float32
    float* st = (float*)d_out;                  // state in d_out, in place
    double* dws = (double*)d_ws;

    k_prep<<<1, 256, 0, stream>>>(ang, dws);
    // Light-cone fused schedule: blocks {1,2,3}, {4,5,6}, {7}; block 0 in init.
    k_H<3, 1><<<1024, 512, 0, stream>>>(st, dws, 1);
    k_L<3, 0><<<1024, 512, 0, stream>>>(st, dws, 1);
    k_H<3, 0><<<1024, 512, 0, stream>>>(st, dws, 4);
    k_L<3, 0><<<1024, 512, 0, stream>>>(st, dws, 4);
    k_H<1, 0><<<1024, 512, 0, stream>>>(st, dws, 7);
    k_L<1, 1><<<1024, 512, 0, stream>>>(st, dws, 7);
    k_final<<<4096, 256, 0, stream>>>(st, dws);
}

// Round 7
// 561.427 us; speedup vs baseline: 1.3534x; 1.0125x over previous
//
#include <hip/hip_runtime.h>

#define NB 8
#define SSIZE (1u << 24)

// Flat index convention (jnp reshape of (2,)*24): wire w <-> bit b = 23-w.
// Stage S_t = RY(bit t) + CNOT(ctrl bit t+1, tgt bit t), applied t = 23..0.
// Light-cone fused schedule (validated r1/r2), windows:
//   H = bits {0,1} u {12..23}  (block idx m = bits 2..11)
//   L = bits {0..13}           (block idx m = bits 14..23)
// Per H+L pair THREE circuit blocks retire => 6 sweeps total.
//
// NUMERICS (validated r2/r4/r5, absmax 0.00586 vs thr 0.00953): state evolves
// in fp64 registers in-kernel; global state between sweeps is fp32. LDS
// transposes exact (lo/hi word passes). Coefs/mean fp64.
//
// STORAGE pi'-layout (ROUND 7): float4-address bits
//   a4 = [0,1]=f12,f13 | [2,3]=f2,f3 | [4..11]=f4..f11 | [12..21]=f14..f23
// k_H: 64B-contiguous granules (4 lanes/line), m = f2..f11 at a4 b2..b11.
// k_L: tile = contiguous 64KB [m<<12 ..]; read/write in STORAGE ORDER.
//   layout1 (lf = tid|jj<<9): lane b0..5 = f12,f13,f2,f3,f4,f5;
//                             tid b6..8 = f6,f7,f8; jj = f9,f10,f11.
//   layout2 (lf = lane|jj<<6|(tid>>6)<<9): jj = f6,f7,f8; tid b6..8 = f9,f10,f11.
// Ladder per block i (S_{11+i}..S0), ALL targets element-local:
//   [L1] S13: lane b1 DPP(ctrl f14=m&1) | S12: lane b0 DPP(ctrl lane b1)
//        S11: jj b2 (rt ctrl f12=lane b0) | S10: jj b1 | S9: jj b0
//   t_fwd
//   [L2] S8: jj b2 (ctrl f9=tid b6) | S7: jj b1 | S6: jj b0
//        S5: lane b5 swap32 (ctrl f6=jj b0) | S4: lane b4 swap16 (ctrl lane b5)
//        S3: lane b3 ror8 | S2: lane b2 sw4 | S1: d b1 (ctrl f2=lane b2) | S0
//   t_back only between blocks. (r6 BUG: old pi put f2,f3 at tid b7,b8 in
//   layout2 -> S3/S2 hit f10/f9 instead; fixed by pi' + this ladder.)
//
// dws layout (doubles): [0]=sum, [8 + k*24 + w]=cos(theta/2), [200+...]=sin.

__global__ void k_prep(const float* __restrict__ ang, double* __restrict__ dws) {
    int t = threadIdx.x;
    if (t == 0) dws[0] = 0.0;
    if (t < NB * 24) {
        double a = 0.5 * (double)ang[t];
        dws[8 + t]   = cos(a);
        dws[200 + t] = sin(a);
    }
}

// ---- helpers ----------------------------------------------------------

__device__ __forceinline__ unsigned sw(unsigned f) {
    return f ^ (((f >> 3) ^ (f >> 5)) & 7u);
}

__device__ __forceinline__ void ry2d(double& a0, double& a1, double c, double s, bool ctl) {
    double w0 = c * a0 - s * a1;
    double w1 = s * a0 + c * a1;
    a0 = ctl ? w1 : w0;
    a1 = ctl ? w0 : w1;
}

// Stage on 8xdouble4 granule: elem bits {0,1}=d, {2,3,4}=register index jj.
template<int TB, int MODE>
__device__ __forceinline__ void stage8d(double4* x, double c, double s) {
#pragma unroll
    for (int j0 = 0; j0 < 8; ++j0) {
        if (j0 & (1 << TB)) continue;
        const int j1 = j0 | (1 << TB);
        const bool ctl = (MODE == 1) || (MODE == 0 && ((j0 >> (TB + 1)) & 1));
        ry2d(x[j0].x, x[j1].x, c, s, ctl);
        ry2d(x[j0].y, x[j1].y, c, s, ctl);
        ry2d(x[j0].z, x[j1].z, c, s, ctl);
        ry2d(x[j0].w, x[j1].w, c, s, ctl);
    }
}

// jj-space stage with RUNTIME per-lane ctrl (uniform over jj).
template<int TB>
__device__ __forceinline__ void stage8d_rt(double4* x, double c, double s, bool ctl) {
#pragma unroll
    for (int j0 = 0; j0 < 8; ++j0) {
        if (j0 & (1 << TB)) continue;
        const int j1 = j0 | (1 << TB);
        ry2d(x[j0].x, x[j1].x, c, s, ctl);
        ry2d(x[j0].y, x[j1].y, c, s, ctl);
        ry2d(x[j0].z, x[j1].z, c, s, ctl);
        ry2d(x[j0].w, x[j1].w, c, s, ctl);
    }
}

__device__ __forceinline__ void coefs_d(unsigned lane, int lb, bool g,
                                        double c, double s, double& cA, double& cP) {
    bool b = (lane >> lb) & 1u;
    cA = g ? (b ? -s : s) : c;
    cP = g ? c : (b ? s : -s);
}

// ---- VALU cross-lane exchange machinery (exact, LDS-free) -------------

// DPP xor on a double (2x mov_dpp on 32b halves). CTRL: 0xB1=quad xor1,
// 0x4E=quad xor2, 0x128=row_ror:8 (== xor 8 within 16-lane row).
template<int CTRL>
__device__ __forceinline__ double dpp_xor_d(double v) {
    int lo = __builtin_amdgcn_mov_dpp(__double2loint(v), CTRL, 0xf, 0xf, true);
    int hi = __builtin_amdgcn_mov_dpp(__double2hiint(v), CTRL, 0xf, 0xf, true);
    return __hiloint2double(hi, lo);
}

template<int CTRL>
__device__ __forceinline__ void lane_stage_dpp(double4* x, double cA, double cP) {
#pragma unroll
    for (int j = 0; j < 8; ++j) {
        double px = dpp_xor_d<CTRL>(x[j].x);
        double py = dpp_xor_d<CTRL>(x[j].y);
        double pz = dpp_xor_d<CTRL>(x[j].z);
        double pw = dpp_xor_d<CTRL>(x[j].w);
        x[j].x = cA * x[j].x + cP * px;
        x[j].y = cA * x[j].y + cP * py;
        x[j].z = cA * x[j].z + cP * pz;
        x[j].w = cA * x[j].w + cP * pw;
    }
}

// ds_swizzle fallback for xor mask 4 (no DPP/permlane pattern).
__device__ __forceinline__ void lane_stage_sw4(double4* x, double cA, double cP) {
#pragma unroll
    for (int j = 0; j < 8; ++j) {
        double px = __shfl_xor(x[j].x, 4, 64);
        double py = __shfl_xor(x[j].y, 4, 64);
        double pz = __shfl_xor(x[j].z, 4, 64);
        double pw = __shfl_xor(x[j].w, 4, 64);
        x[j].x = cA * x[j].x + cP * px;
        x[j].y = cA * x[j].y + cP * py;
        x[j].z = cA * x[j].z + cP * pz;
        x[j].w = cA * x[j].w + cP * pw;
    }
}

// permlane swap on a double pair: word-wise. After swap32: each element's
// (lane-b5=0, lane-b5=1) components co-located; reg index = target bit,
// current lane>=32 encodes the old reg parity (jj b0). Involution.
// permlane16_swap: same with 16-rows -> reg index = lane-b4 bit; lane b5
// is preserved.
template<bool IS32>
__device__ __forceinline__ void swap_pair_d(double& a, double& b) {
    int alo = __double2loint(a), ahi = __double2hiint(a);
    int blo = __double2loint(b), bhi = __double2hiint(b);
    if (IS32) {
        auto r0 = __builtin_amdgcn_permlane32_swap(alo, blo, false, false);
        auto r1 = __builtin_amdgcn_permlane32_swap(ahi, bhi, false, false);
        alo = r0[0]; blo = r0[1]; ahi = r1[0]; bhi = r1[1];
    } else {
        auto r0 = __builtin_amdgcn_permlane16_swap(alo, blo, false, false);
        auto r1 = __builtin_amdgcn_permlane16_swap(ahi, bhi, false, false);
        alo = r0[0]; blo = r0[1]; ahi = r1[0]; bhi = r1[1];
    }
    a = __hiloint2double(ahi, alo);
    b = __hiloint2double(bhi, blo);
}

// Stage with target lane-bit5 (IS32, ctrl = jj b0 == lane>=32 in swapped view)
// or lane-bit4 (!IS32, ctrl = lane b5 == lane>=32, preserved by swap16).
// g? (al,be,ga,de)=(s,c,c,-s) : (c,-s,s,c).
template<bool IS32>
__device__ __forceinline__ void stage_swap(double4* x, double c, double s, bool gsel) {
    double al = gsel ? s : c, be = gsel ? c : -s;
    double ga = gsel ? c : s, de = gsel ? -s : c;
#pragma unroll
    for (int p = 0; p < 4; ++p) {
        double4& A = x[2 * p];
        double4& B = x[2 * p + 1];
        swap_pair_d<IS32>(A.x, B.x); swap_pair_d<IS32>(A.y, B.y);
        swap_pair_d<IS32>(A.z, B.z); swap_pair_d<IS32>(A.w, B.w);
        double ux = A.x, vx = B.x, uy = A.y, vy = B.y;
        double uz = A.z, vz = B.z, uw = A.w, vw = B.w;
        A.x = al * ux + be * vx;  B.x = ga * ux + de * vx;
        A.y = al * uy + be * vy;  B.y = ga * uy + de * vy;
        A.z = al * uz + be * vz;  B.z = ga * uz + de * vz;
        A.w = al * uw + be * vw;  B.w = ga * uw + de * vw;
        swap_pair_d<IS32>(A.x, B.x); swap_pair_d<IS32>(A.y, B.y);
        swap_pair_d<IS32>(A.z, B.z); swap_pair_d<IS32>(A.w, B.w);
    }
}

// S1 (tgt d1, ctrl = runtime bool g1) then S0 (tgt d0, ctrl d1).
__device__ __forceinline__ void dstages_d(double4* x, double c1, double s1, bool g1,
                                          double c0, double s0) {
#pragma unroll
    for (int j = 0; j < 8; ++j) {
        ry2d(x[j].x, x[j].z, c1, s1, g1);
        ry2d(x[j].y, x[j].w, c1, s1, g1);
        ry2d(x[j].x, x[j].y, c0, s0, false);
        ry2d(x[j].z, x[j].w, c0, s0, true);
    }
}

// x = (0.6*tanh(0.1*2^23*v^2))^0.15; small-z series avoids cancellation.
__device__ __forceinline__ float xform(float z) {
    float e2 = __builtin_amdgcn_exp2f(z * 2.8853900817779268f);   // e^(2z)
    float big = 1.0f - 2.0f * __builtin_amdgcn_rcpf(e2 + 1.0f);
    float z2 = z * z;
    float small_ = z * (1.0f - 0.33333333f * z2 * (1.0f - 0.4f * z2));
    float t = (z < 0.04f) ? small_ : big;
    return __builtin_amdgcn_exp2f(0.15f * __builtin_amdgcn_logf(0.6f * t));
}

// ---- exact fp64 LDS transposes (lo/hi word two-pass through 64KB tile) ---
// layout1: lf = tid | (jj<<9)   layout2: lf = lane | (jj<<6) | ((tid>>6)<<9)

__device__ __forceinline__ float4 lo4(const double4 v) {
    return make_float4(__int_as_float(__double2loint(v.x)),
                       __int_as_float(__double2loint(v.y)),
                       __int_as_float(__double2loint(v.z)),
                       __int_as_float(__double2loint(v.w)));
}
__device__ __forceinline__ float4 hi4(const double4 v) {
    return make_float4(__int_as_float(__double2hiint(v.x)),
                       __int_as_float(__double2hiint(v.y)),
                       __int_as_float(__double2hiint(v.z)),
                       __int_as_float(__double2hiint(v.w)));
}
__device__ __forceinline__ double4 mk4(const float4 h, const float4 l) {
    return make_double4(__hiloint2double(__float_as_int(h.x), __float_as_int(l.x)),
                        __hiloint2double(__float_as_int(h.y), __float_as_int(l.y)),
                        __hiloint2double(__float_as_int(h.z), __float_as_int(l.z)),
                        __hiloint2double(__float_as_int(h.w), __float_as_int(l.w)));
}

__device__ __forceinline__ void t_fwd_d(float4* T4, double4* x, unsigned tid,
                                        unsigned lane, unsigned hi, bool protect) {
    if (protect) __syncthreads();
#pragma unroll
    for (int jj = 0; jj < 8; ++jj) T4[sw(tid | (jj << 9))] = lo4(x[jj]);
    __syncthreads();
    float4 tl[8];
#pragma unroll
    for (int jj = 0; jj < 8; ++jj) tl[jj] = T4[sw(lane | (jj << 6) | hi)];
    __syncthreads();
#pragma unroll
    for (int jj = 0; jj < 8; ++jj) T4[sw(tid | (jj << 9))] = hi4(x[jj]);
    __syncthreads();
#pragma unroll
    for (int jj = 0; jj < 8; ++jj)
        x[jj] = mk4(T4[sw(lane | (jj << 6) | hi)], tl[jj]);
}

__device__ __forceinline__ void t_back_d(float4* T4, double4* x, unsigned tid,
                                         unsigned lane, unsigned hi) {
    __syncthreads();
#pragma unroll
    for (int jj = 0; jj < 8; ++jj) T4[sw(lane | (jj << 6) | hi)] = lo4(x[jj]);
    __syncthreads();
    float4 tl[8];
#pragma unroll
    for (int jj = 0; jj < 8; ++jj) tl[jj] = T4[sw(tid | (jj << 9))];
    __syncthreads();
#pragma unroll
    for (int jj = 0; jj < 8; ++jj) T4[sw(lane | (jj << 6) | hi)] = hi4(x[jj]);
    __syncthreads();
#pragma unroll
    for (int jj = 0; jj < 8; ++jj)
        x[jj] = mk4(T4[sw(tid | (jj << 9))], tl[jj]);
}

// Three jj-space stages; START: 0=all three, 1=skip top, 2=only lowest.
template<int START>
__device__ __forceinline__ void jj_trio_d(double4* x, const double* c, const double* s,
                                          bool top_on) {
    if (START == 0) {
        if (top_on) stage8d<2, 1>(x, c[0], s[0]);
        else        stage8d<2,-1>(x, c[0], s[0]);
    }
    if (START <= 1) stage8d<1, 0>(x, c[1], s[1]);
    stage8d<0, 0>(x, c[2], s[2]);
}

// Lane stages, targets lane bits 5..0; first ctrl = jj bit 0, rest ctrl = lane
// bit (target+1). N = how many from the top (4..6). VALU cross-lane except bit2.
template<int N>
__device__ __forceinline__ void lane_ladder_v(double4* x, unsigned lane,
                                              const double* c, const double* s) {
    const bool hi5 = lane >= 32;
    stage_swap<true>(x, c[0], s[0], hi5);                 // tgt bit5, ctrl jj0
    if (N > 1) stage_swap<false>(x, c[1], s[1], hi5);     // tgt bit4, ctrl bit5
    if (N > 2) { double cA, cP; coefs_d(lane, 3, (lane >> 4) & 1, c[2], s[2], cA, cP);
                 lane_stage_dpp<0x128>(x, cA, cP); }      // tgt bit3, row_ror:8
    if (N > 3) { double cA, cP; coefs_d(lane, 2, (lane >> 3) & 1, c[3], s[3], cA, cP);
                 lane_stage_sw4(x, cA, cP); }             // tgt bit2, ds_swizzle
    if (N > 4) { double cA, cP; coefs_d(lane, 1, (lane >> 2) & 1, c[4], s[4], cA, cP);
                 lane_stage_dpp<0x4E>(x, cA, cP); }       // tgt bit1, quad xor2
    if (N > 5) { double cA, cP; coefs_d(lane, 0, (lane >> 1) & 1, c[5], s[5], cA, cP);
                 lane_stage_dpp<0xB1>(x, cA, cP); }       // tgt bit0, quad xor1
}

__device__ __forceinline__ double4 d4_of(const float4 f) {
    return make_double4((double)f.x, (double)f.y, (double)f.z, (double)f.w);
}
__device__ __forceinline__ float4 f4_of(const double4 d) {
    return make_float4((float)d.x, (float)d.y, (float)d.z, (float)d.w);
}

// ---- H sweep block iteration, compile-time recursion over I -----------
// Block I (circuit block kbase+I) applies S23..S_{12+I}.
template<int I, int NBLK>
__device__ __forceinline__ void h_block(double4* x, float4* T4,
                                        const double* __restrict__ dws, int kbase,
                                        unsigned tid, unsigned lane, unsigned hi) {
    const double* C = dws + 8   + (kbase + I) * 24;
    const double* S = dws + 200 + (kbase + I) * 24;
    jj_trio_d<0>(x, C + 0, S + 0, false);               // S23 (RY only), S22, S21
    t_fwd_d(T4, x, tid, lane, hi, I > 0);
    jj_trio_d<0>(x, C + 3, S + 3, (tid & 64u) != 0);    // S20 (ctrl w9=tid6), S19, S18
    lane_ladder_v<6 - I>(x, lane, C + 6, S + 6);        // S17..S_{12+I}
    if constexpr (I < NBLK - 1) {
        t_back_d(T4, x, tid, lane, hi);
        h_block<I + 1, NBLK>(x, T4, dws, kbase, tid, lane, hi);
    }
}

// ---- H sweep: window bits {0,1} u {12..23}; m = global bits {2..11}.
// pi'-layout: mbase4 = f2,f3 at a4 b2,b3 and f4..f11 at a4 b4..b11;
// window: w&3 (f12,f13) at a4 b0,b1; w>>2 (f14..f23) at a4 b12..21.
// => 64B-contiguous granules per 4 lanes.
template<int NBLK, int INIT>
__global__ __launch_bounds__(512, 2) void k_H(float* __restrict__ st,
                                              const double* __restrict__ dws,
                                              int kbase) {
    __shared__ float4 T4[4096];   // 64 KB
    const unsigned bid = blockIdx.x;
    // XCD-contiguity swizzle: each XCD gets a contiguous m-range.
    const unsigned m = (bid >> 3) | ((bid & 7u) << 7);
    const unsigned tid = threadIdx.x;
    const unsigned lane = tid & 63u;
    const unsigned hi = (tid >> 6) << 9;
    const unsigned mbase4 = ((m & 3u) << 2) | ((m >> 2) << 4);
    float4* G4 = reinterpret_cast<float4*>(st);
    double4 x[8];

    if (INIT) {
        // Block-0 analytic: amp(f) = prod_b phi_b(gray_b), gray = f ^ (f>>1).
        // f bits: f{0,1}=d; f{2..11}=m; f{12..20}=tid{0..8}; f{21..23}=jj.
        const double* C0 = dws + 8;
        const double* S0 = dws + 200;
        double P = 1.0;
#pragma unroll
        for (int b = 2; b <= 10; ++b) {
            unsigned g = ((m >> (b - 2)) ^ (m >> (b - 1))) & 1u;
            P *= g ? S0[23 - b] : C0[23 - b];
        }
        { unsigned g = ((m >> 9) ^ tid) & 1u; P *= g ? S0[12] : C0[12]; }   // b=11
#pragma unroll
        for (int b = 12; b <= 19; ++b) {
            unsigned g = ((tid >> (b - 12)) ^ (tid >> (b - 11))) & 1u;
            P *= g ? S0[23 - b] : C0[23 - b];
        }
        double D[4];
#pragma unroll
        for (int d = 0; d < 4; ++d) {
            unsigned g0 = (d ^ (d >> 1)) & 1u;
            unsigned g1 = ((d >> 1) ^ m) & 1u;
            D[d] = (g0 ? S0[23] : C0[23]) * (g1 ? S0[22] : C0[22]);
        }
        unsigned t8 = (tid >> 8) & 1u;
#pragma unroll
        for (int jj = 0; jj < 8; ++jj) {
            unsigned g20 = (t8 ^ (unsigned)jj) & 1u;
            unsigned g21 = ((unsigned)jj ^ ((unsigned)jj >> 1)) & 1u;
            unsigned g22 = (((unsigned)jj >> 1) ^ ((unsigned)jj >> 2)) & 1u;
            unsigned g23 = (((unsigned)jj >> 2)) & 1u;
            double J = (g20 ? S0[3] : C0[3]) * (g21 ? S0[2] : C0[2]) *
                       (g22 ? S0[1] : C0[1]) * (g23 ? S0[0] : C0[0]);
            double PJ = P * J;
            x[jj] = make_double4(PJ * D[0], PJ * D[1], PJ * D[2], PJ * D[3]);
        }
    } else {
#pragma unroll
        for (int jj = 0; jj < 8; ++jj) {
            unsigned w = tid | (jj << 9);
            x[jj] = d4_of(G4[mbase4 | (w & 3u) | ((w >> 2) << 12)]);
        }
    }

    h_block<0, NBLK>(x, T4, dws, kbase, tid, lane, hi);

    // store from layout2 (pi'-layout)
#pragma unroll
    for (int jj = 0; jj < 8; ++jj) {
        unsigned w = lane | (jj << 6) | hi;
        G4[mbase4 | (w & 3u) | ((w >> 2) << 12)] = f4_of(x[jj]);
    }
}

// ---- L sweep: window bits {0..13}; m = global bits {14..23}.
// Tile read/written IN STORAGE ORDER (contiguous 64KB). See header for the
// pi' element maps and the per-block ladder decomposition.
template<int NBLK, int FUSE>
__global__ __launch_bounds__(512, 2) void k_L(float* __restrict__ st,
                                              double* __restrict__ dws,
                                              int kbase) {
    __shared__ float4 T4[4096];   // 64 KB
    const unsigned m = blockIdx.x;
    const unsigned tid = threadIdx.x;
    const unsigned lane = tid & 63u;
    const unsigned hi = (tid >> 6) << 9;
    float4* G4 = reinterpret_cast<float4*>(st) + (m << 12);
    double4 x[8];
#pragma unroll
    for (int jj = 0; jj < 8; ++jj) x[jj] = d4_of(G4[tid + (jj << 9)]);   // contiguous

#pragma unroll
    for (int i = 0; i < NBLK; ++i) {
        const double* C = dws + 8   + (kbase + i) * 24;
        const double* S = dws + 200 + (kbase + i) * 24;
        // ---- layout1: lane b0..5=f12,f13,f2,f3,f4,f5; tid b6..8=f6,f7,f8; jj=f9,f10,f11
        if (i >= 2) {   // S13: tgt f13=lane b1, ctrl f14 = m&1
            double cA, cP; coefs_d(lane, 1, (m & 1u) != 0, C[10], S[10], cA, cP);
            lane_stage_dpp<0x4E>(x, cA, cP);
        }
        if (i >= 1) {   // S12: tgt f12=lane b0, ctrl f13 = lane b1
            double cA, cP; coefs_d(lane, 0, (lane >> 1) & 1, C[11], S[11], cA, cP);
            lane_stage_dpp<0xB1>(x, cA, cP);
        }
        stage8d_rt<2>(x, C[12], S[12], (lane & 1u) != 0);   // S11: tgt jj b2, ctrl f12=lane b0
        stage8d<1, 0>(x, C[13], S[13]);                     // S10: tgt jj b1, ctrl f11=jj b2
        stage8d<0, 0>(x, C[14], S[14]);                     // S9 : tgt jj b0, ctrl f10=jj b1
        t_fwd_d(T4, x, tid, lane, hi, i > 0);
        // ---- layout2: jj=f6,f7,f8; tid b6..8=f9,f10,f11
        if (tid & 64u) stage8d<2, 1>(x, C[15], S[15]);      // S8: tgt jj b2, ctrl f9=tid b6
        else           stage8d<2,-1>(x, C[15], S[15]);
        stage8d<1, 0>(x, C[16], S[16]);                     // S7: tgt jj b1, ctrl f8=jj b2
        stage8d<0, 0>(x, C[17], S[17]);                     // S6: tgt jj b0, ctrl f7=jj b1
        stage_swap<true >(x, C[18], S[18], lane >= 32);     // S5: tgt lane b5, ctrl f6=jj b0
        stage_swap<false>(x, C[19], S[19], lane >= 32);     // S4: tgt lane b4, ctrl f5=lane b5
        { double cA, cP; coefs_d(lane, 3, (lane >> 4) & 1, C[20], S[20], cA, cP);
          lane_stage_dpp<0x128>(x, cA, cP); }               // S3: tgt lane b3, ctrl f4=lane b4
        { double cA, cP; coefs_d(lane, 2, (lane >> 3) & 1, C[21], S[21], cA, cP);
          lane_stage_sw4(x, cA, cP); }                      // S2: tgt lane b2, ctrl f3=lane b3
        dstages_d(x, C[22], S[22], ((lane >> 2) & 1u) != 0, // S1: tgt d1, ctrl f2=lane b2
                  C[23], S[23]);                            // S0: tgt d0, ctrl d1
        if (i < NBLK - 1) t_back_d(T4, x, tid, lane, hi);
    }

    if (FUSE) {
        // Transform, then LDS-redistribute fp32 outputs into TRUE layout.
        // layout2 element -> true local f4-index t4 (f2..f13 at bits 0..11):
        //   t4 = (lane>>2)&0xF /*f2..f5*/ | jj<<4 /*f6..f8*/
        //      | ((tid>>6)&7)<<7 /*f9..f11*/ | (lane&3)<<10 /*f12,f13*/
        double lsum = 0.0;
        __syncthreads();   // T4 last read by t_fwd
#pragma unroll
        for (int jj = 0; jj < 8; ++jj) {
            double* v = &x[jj].x;
            float4 o;
            float* ov = &o.x;
#pragma unroll
            for (int d = 0; d < 4; ++d) {
                float z = (float)(838860.8 * v[d] * v[d]);
                float xf = xform(z);
                ov[d] = xf;
                lsum += (double)xf;
            }
            unsigned t4 = ((lane >> 2) & 0xFu) | ((unsigned)jj << 4)
                        | (((tid >> 6) & 7u) << 7) | ((lane & 3u) << 10);
            T4[sw(t4)] = o;
        }
        __syncthreads();
#pragma unroll
        for (int jj = 0; jj < 8; ++jj)
            G4[tid | (jj << 9)] = T4[sw(tid | (jj << 9))];
#pragma unroll
        for (int o = 32; o > 0; o >>= 1) lsum += __shfl_down(lsum, o, 64);
        __syncthreads();   // T4 output reads done; safe to reuse as wsum
        double* wsum = reinterpret_cast<double*>(T4);
        if ((tid & 63u) == 0) wsum[tid >> 6] = lsum;
        __syncthreads();
        if (tid == 0) {
            double b = 0.0;
#pragma unroll
            for (int i = 0; i < 8; ++i) b += wsum[i];
            atomicAdd(dws, b);
        }
    } else {
        // contiguous pi'-layout store from layout2 (element lf = lane|jj<<6|hi)
#pragma unroll
        for (int jj = 0; jj < 8; ++jj)
            G4[lane | (jj << 6) | hi] = f4_of(x[jj]);
    }
}

__global__ void k_final(float* __restrict__ st, const double* __restrict__ dws) {
    unsigned idx = blockIdx.x * blockDim.x + threadIdx.x;
    unsigned stride = gridDim.x * blockDim.x;
    float mean = (float)(dws[0] * (1.0 / 16777216.0));
    float4* G4 = reinterpret_cast<float4*>(st);
    for (unsigned q = idx; q < (SSIZE / 4); q += stride) {
        float4 v = G4[q];
        v.x -= mean; v.y -= mean; v.z -= mean; v.w -= mean;
        G4[q] = v;
    }
}

extern "C" void kernel_launch(void* const* d_in, const int* in_sizes, int n_in,
                              void* d_out, int out_size, void* d_ws, size_t ws_size,
                              hipStream_t stream) {
    const float* ang = (const float*)d_in[0];   // [8][24] float32
    float* st = (float*)d_out;                  // state in d_out, in place
    double* dws = (double*)d_ws;

    k_prep<<<1, 256, 0, stream>>>(ang, dws);
    // Light-cone fused schedule: blocks {1,2,3}, {4,5,6}, {7}; block 0 in init.
    k_H<3, 1><<<1024, 512, 0, stream>>>(st, dws, 1);
    k_L<3, 0><<<1024, 512, 0, stream>>>(st, dws, 1);
    k_H<3, 0><<<1024, 512, 0, stream>>>(st, dws, 4);
    k_L<3, 0><<<1024, 512, 0, stream>>>(st, dws, 4);
    k_H<1, 0><<<1024, 512, 0, stream>>>(st, dws, 7);
    k_L<1, 1><<<1024, 512, 0, stream>>>(st, dws, 7);
    k_final<<<4096, 256, 0, stream>>>(st, dws);
}